// Round 4
// baseline (181.787 us; speedup 1.0000x reference)
//
#include <hip/hip_runtime.h>

// ---------------------------------------------------------------------------
// HierarchicalAffinityLoss on MI355X, fp16-MFMA path, round 4.
// loss = mean_r relu(maxDot_diff(r) - minDot_same(r) + 0.3), dots of
// row-normalized embeddings. Self-exclusion dropped (self-dot=1.0 never the
// min over ~2000 same-family dots near 0; verified round 3, absmax 0.0).
// Round-4: (a) global_load_lds width-16 staging (swizzle via source perm),
// (b) 768-block flattened task grid + encoded atomic min/max merge,
// (c) finalize reads 2*B words instead of NS*B*2.
// ---------------------------------------------------------------------------

typedef __attribute__((ext_vector_type(8))) _Float16 half8;  // MFMA A/B frag
typedef __attribute__((ext_vector_type(4))) float floatx4;   // MFMA C/D
typedef __attribute__((ext_vector_type(4))) unsigned short ushort4v;

constexpr int D    = 256;  // embedding dim
constexpr int GRID = 768;  // 3 blocks/CU x 256 CUs (VGPR-limited residency)
#define MARGIN 0.3f
// packed family table {0,1,2,1,3,3}, 3 bits each
#define FAM_PACKED 111240

// order-preserving float<->uint encoding for atomicMin/Max
static __device__ __forceinline__ unsigned enc(float f) {
  unsigned b = __float_as_uint(f);
  return b ^ ((unsigned)((int)b >> 31) | 0x80000000u);
}
static __device__ __forceinline__ float dec(unsigned e) {
  unsigned b = (e & 0x80000000u) ? (e ^ 0x80000000u) : ~e;
  return __uint_as_float(b);
}

// async 16B global -> LDS (wave-uniform LDS base + lane*16)
static __device__ __forceinline__ void ld_g2l16(const unsigned short* g,
                                                unsigned short* l) {
  __builtin_amdgcn_global_load_lds(
      (const __attribute__((address_space(1))) unsigned int*)(const void*)g,
      (__attribute__((address_space(3))) unsigned int*)(void*)l, 16, 0, 0);
}

// K1: one wave per row -> Eh[row][:] = fp16(E/||E||), fam[row], enc inits
__global__ __launch_bounds__(256) void prep_kernel(
    const float* __restrict__ E, const int* __restrict__ labels,
    unsigned short* __restrict__ Eh, int* __restrict__ fam,
    unsigned* __restrict__ encMin, unsigned* __restrict__ encMax, int B) {
  int row  = blockIdx.x * 4 + (threadIdx.x >> 6);
  int lane = threadIdx.x & 63;
  if (row >= B) return;
  float4 v = *(const float4*)&E[(long)row * D + lane * 4];
  float s = v.x * v.x + v.y * v.y + v.z * v.z + v.w * v.w;
#pragma unroll
  for (int o = 1; o < 64; o <<= 1) s += __shfl_xor(s, o);
  float rn = 1.0f / sqrtf(s);
  ushort4v o4;
  o4.x = __builtin_bit_cast(unsigned short, (_Float16)(v.x * rn));
  o4.y = __builtin_bit_cast(unsigned short, (_Float16)(v.y * rn));
  o4.z = __builtin_bit_cast(unsigned short, (_Float16)(v.z * rn));
  o4.w = __builtin_bit_cast(unsigned short, (_Float16)(v.w * rn));
  *(ushort4v*)&Eh[(long)row * D + lane * 4] = o4;
  if (lane == 0) {
    int lab = labels[row];
    int labc = lab < 0 ? 0 : (lab > 5 ? 5 : lab);
    fam[row] = (lab < 6) ? ((FAM_PACKED >> (3 * labc)) & 7) : -1;
  }
  if (lane == 1) {
    encMin[row] = enc(4.0f);    // sentinel: "no same seen"
    encMax[row] = enc(-4.0f);   // sentinel: "no diff seen"
  }
}

// K2: MFMA Gram (never materialized) + fused masked row min/max.
// 256 threads (4 waves, 2x2 of 64x64), tile 128x128, BK=64, 16x16x32 f16.
// LDS chunk c (16B) holds global chunk (row=c>>3, kc=(c&7)^(row&7)) -- the
// XOR swizzle realized by permuting SOURCE addresses for global_load_lds.
__global__ __launch_bounds__(256) void gram_mfma_kernel(
    const unsigned short* __restrict__ Eh, const int* __restrict__ fam,
    unsigned* __restrict__ encMin, unsigned* __restrict__ encMax, int B) {
  __shared__ unsigned short As[128 * 64];   // 16 KB
  __shared__ unsigned short Bs[128 * 64];   // 16 KB

  const int tid = threadIdx.x;
  const int l   = tid & 63;
  const int wid = tid >> 6;
  const int wy  = wid >> 1, wx = wid & 1;
  const int m   = l & 15, q = l >> 4, sel = l & 7;

  // per-lane staging source offsets (task-independent): wave wid stages
  // LDS chunks [wid*256, wid*256+256) in 4 instructions of 64 lanes.
  const unsigned short* srcRel[4];
#pragma unroll
  for (int t = 0; t < 4; ++t) {
    int c   = wid * 256 + t * 64 + l;
    int row = c >> 3;
    int kc  = (c & 7) ^ (row & 7);
    srcRel[t] = Eh + (long)row * D + kc * 8;
  }

  const int nct    = B / 128;          // 64 col tiles
  const int nTasks = (B / 128) * nct;  // 4096 (rt,ct) pairs
  const int t0 = (int)(((long)blockIdx.x * nTasks) / gridDim.x);
  const int t1 = (int)(((long)(blockIdx.x + 1) * nTasks) / gridDim.x);

  for (int task = t0; task < t1; ++task) {
    const int rt = task / nct, ct = task - rt * nct;
    const int r0 = rt * 128, c0 = ct * 128;
    const long aOff = (long)r0 * D, bOff = (long)c0 * D;

    float minS[16], maxD[16];
    int famR[16];
#pragma unroll
    for (int i = 0; i < 16; ++i) { minS[i] = 4.0f; maxD[i] = -4.0f; }
#pragma unroll
    for (int mi = 0; mi < 4; ++mi)
#pragma unroll
      for (int r = 0; r < 4; ++r)
        famR[mi * 4 + r] = fam[r0 + wy * 64 + mi * 16 + q * 4 + r];

    floatx4 acc[4][4];
#pragma unroll
    for (int mi = 0; mi < 4; ++mi)
#pragma unroll
      for (int nj = 0; nj < 4; ++nj) acc[mi][nj] = (floatx4)0.0f;

#pragma unroll 1
    for (int kb = 0; kb < D; kb += 64) {
      __syncthreads();
#pragma unroll
      for (int t = 0; t < 4; ++t) {
        ld_g2l16(srcRel[t] + aOff + kb, &As[(wid * 256 + t * 64) * 8]);
        ld_g2l16(srcRel[t] + bOff + kb, &Bs[(wid * 256 + t * 64) * 8]);
      }
      __syncthreads();   // drains vmcnt -> LDS valid
#pragma unroll
      for (int kh = 0; kh < 2; ++kh) {
        const int lc = kh * 4 + q;
        half8 a[4], b[4];
#pragma unroll
        for (int mi = 0; mi < 4; ++mi)
          a[mi] = *(const half8*)
              &As[(wy * 64 + mi * 16 + m) * 64 + ((lc ^ sel) << 3)];
#pragma unroll
        for (int nj = 0; nj < 4; ++nj)
          b[nj] = *(const half8*)
              &Bs[(wx * 64 + nj * 16 + m) * 64 + ((lc ^ sel) << 3)];
#pragma unroll
        for (int mi = 0; mi < 4; ++mi)
#pragma unroll
          for (int nj = 0; nj < 4; ++nj)
            acc[mi][nj] = __builtin_amdgcn_mfma_f32_16x16x32_f16(
                a[mi], b[nj], acc[mi][nj], 0, 0, 0);
      }
    }
    // fused epilogue: masked min/max for this 128x128 tile
    int famC[4];
#pragma unroll
    for (int nj = 0; nj < 4; ++nj)
      famC[nj] = fam[c0 + wx * 64 + nj * 16 + m];
#pragma unroll
    for (int mi = 0; mi < 4; ++mi)
#pragma unroll
      for (int nj = 0; nj < 4; ++nj) {
#pragma unroll
        for (int r = 0; r < 4; ++r) {
          float d = acc[mi][nj][r];          // C/D: col=l&15, row=q*4+r
          bool same = (famR[mi * 4 + r] == famC[nj]);
          minS[mi * 4 + r] = fminf(minS[mi * 4 + r], same ? d : 4.0f);
          maxD[mi * 4 + r] = fmaxf(maxD[mi * 4 + r], same ? -4.0f : d);
        }
      }
    // reduce across the 16 col lanes, then one atomic pair per row
#pragma unroll
    for (int o = 1; o < 16; o <<= 1)
#pragma unroll
      for (int i = 0; i < 16; ++i) {
        minS[i] = fminf(minS[i], __shfl_xor(minS[i], o));
        maxD[i] = fmaxf(maxD[i], __shfl_xor(maxD[i], o));
      }
    if (m == 0) {
#pragma unroll
      for (int mi = 0; mi < 4; ++mi)
#pragma unroll
        for (int r = 0; r < 4; ++r) {
          int gr = r0 + wy * 64 + mi * 16 + q * 4 + r;
          atomicMin(&encMin[gr], enc(minS[mi * 4 + r]));
          atomicMax(&encMax[gr], enc(maxD[mi * 4 + r]));
        }
    }
  }
}

// K3: decode per-row extremes, mean loss over valid rows (64 KB of reads).
__global__ __launch_bounds__(256) void finalize_kernel(
    const unsigned* __restrict__ encMin, const unsigned* __restrict__ encMax,
    float* __restrict__ out, int B) {
  __shared__ float ssum[4];
  __shared__ int   scnt[4];
  float sum = 0.0f;
  int cnt = 0;
  for (int r = threadIdx.x; r < B; r += 256) {
    float mn = dec(encMin[r]);
    float mx = dec(encMax[r]);
    if (mn < 3.0f && mx > -3.0f) {   // has same && has diff
      sum += fmaxf(mx - mn + MARGIN, 0.0f);
      cnt += 1;
    }
  }
#pragma unroll
  for (int o = 1; o < 64; o <<= 1) {
    sum += __shfl_xor(sum, o);
    cnt += __shfl_xor(cnt, o);
  }
  int wave = threadIdx.x >> 6;
  if ((threadIdx.x & 63) == 0) { ssum[wave] = sum; scnt[wave] = cnt; }
  __syncthreads();
  if (threadIdx.x == 0) {
    float S = 0.0f; int C = 0;
#pragma unroll
    for (int w = 0; w < 4; ++w) { S += ssum[w]; C += scnt[w]; }
    out[0] = S / (float)(C > 0 ? C : 1);
  }
}

extern "C" void kernel_launch(void* const* d_in, const int* in_sizes, int n_in,
                              void* d_out, int out_size, void* d_ws, size_t ws_size,
                              hipStream_t stream) {
  const float* E      = (const float*)d_in[0];
  const int*   labels = (const int*)d_in[1];
  float*       out    = (float*)d_out;
  const int B = in_sizes[1];   // 8192

  // ws: Eh[B*D] fp16 (4MB) | fam[B] | encMin[B] | encMax[B]
  unsigned short* Eh = (unsigned short*)d_ws;
  int* fam           = (int*)(Eh + (size_t)B * D);
  unsigned* encMin   = (unsigned*)(fam + B);
  unsigned* encMax   = encMin + B;

  prep_kernel<<<dim3(B / 4), 256, 0, stream>>>(E, labels, Eh, fam,
                                               encMin, encMax, B);
  gram_mfma_kernel<<<dim3(GRID), 256, 0, stream>>>(Eh, fam, encMin, encMax, B);
  finalize_kernel<<<1, 256, 0, stream>>>(encMin, encMax, out, B);
}

// Round 5
// 155.621 us; speedup vs baseline: 1.1681x; 1.1681x over previous
//
#include <hip/hip_runtime.h>

// ---------------------------------------------------------------------------
// HierarchicalAffinityLoss on MI355X, fp16-MFMA, round 5.
// loss = mean_r relu(maxDot_diff(r) - minDot_same(r) + 0.3), dots of
// row-normalized embeddings. Self-exclusion dropped (self-dot=1.0 never the
// min over ~2000 same-family dots near 0; verified rounds 3/4, absmax 0.0).
// Round-5: single-wave workgroups -> __syncthreads is a wave-local vmcnt
// drain (no cross-wave barrier coupling); A-fragments direct global->VGPR
// (k-contiguous layout); B via global_load_lds into 8 KB swizzled LDS;
// no atomics (fp16-packed per-slice partials + parallel reduce).
// ---------------------------------------------------------------------------

typedef __attribute__((ext_vector_type(8))) _Float16 half8;  // MFMA A/B frag
typedef __attribute__((ext_vector_type(4))) float floatx4;   // MFMA C/D
typedef __attribute__((ext_vector_type(4))) unsigned short ushort4v;

constexpr int D   = 256;  // embedding dim
constexpr int CTG = 4;    // col-tiles per block (64 cols each)
#define MARGIN 0.3f
// packed family table {0,1,2,1,3,3}, 3 bits each
#define FAM_PACKED 111240

// async 16B global -> LDS (wave-uniform LDS base + lane*16)
static __device__ __forceinline__ void ld_g2l16(const unsigned short* g,
                                                unsigned short* l) {
  __builtin_amdgcn_global_load_lds(
      (const __attribute__((address_space(1))) unsigned int*)(const void*)g,
      (__attribute__((address_space(3))) unsigned int*)(void*)l, 16, 0, 0);
}

// K1: one wave per row -> Eh[row][:] = fp16(E/||E||), fam[row]; zero accums
__global__ __launch_bounds__(256) void prep_kernel(
    const float* __restrict__ E, const int* __restrict__ labels,
    unsigned short* __restrict__ Eh, int* __restrict__ fam,
    float* __restrict__ sumAcc, int* __restrict__ cntAcc, int B) {
  if (blockIdx.x == 0 && threadIdx.x == 0) { sumAcc[0] = 0.0f; cntAcc[0] = 0; }
  int row  = blockIdx.x * 4 + (threadIdx.x >> 6);
  int lane = threadIdx.x & 63;
  if (row >= B) return;
  float4 v = *(const float4*)&E[(long)row * D + lane * 4];
  float s = v.x * v.x + v.y * v.y + v.z * v.z + v.w * v.w;
#pragma unroll
  for (int o = 1; o < 64; o <<= 1) s += __shfl_xor(s, o);
  float rn = 1.0f / sqrtf(s);
  ushort4v o4;
  o4.x = __builtin_bit_cast(unsigned short, (_Float16)(v.x * rn));
  o4.y = __builtin_bit_cast(unsigned short, (_Float16)(v.y * rn));
  o4.z = __builtin_bit_cast(unsigned short, (_Float16)(v.z * rn));
  o4.w = __builtin_bit_cast(unsigned short, (_Float16)(v.w * rn));
  *(ushort4v*)&Eh[(long)row * D + lane * 4] = o4;
  if (lane == 0) {
    int lab = labels[row];
    int labc = lab < 0 ? 0 : (lab > 5 ? 5 : lab);
    fam[row] = (lab < 6) ? ((FAM_PACKED >> (3 * labc)) & 7) : -1;
  }
}

// K2: one wave per block; 64x64 MFMA tile, CTG col-tiles per block.
// Per kb-step: 8 global_load_lds (B, swizzled), 8 direct a-frag loads,
// wave-local barrier (vmcnt drain), 8 ds_read_b128, 32 MFMA.
__global__ __launch_bounds__(64) void gram_kernel(
    const unsigned short* __restrict__ Eh, const int* __restrict__ fam,
    unsigned* __restrict__ partMM, int B) {
  __shared__ unsigned short Bs[64 * 64];   // 8 KB

  const int l = threadIdx.x;
  const int m = l & 15, q = l >> 4;

  const int ncg = (B / 64) / CTG;          // 32 col-groups
  const int rt = blockIdx.x / ncg;
  const int cg = blockIdx.x - rt * ncg;
  const int r0 = rt * 64;

  // B-staging source offsets (elements), task-independent:
  // instr t stages LDS chunks c = t*64+l; row=c>>3, kc=(c&7)^(row&7)
  int srcRel[8];
#pragma unroll
  for (int t = 0; t < 8; ++t) {
    int c = t * 64 + l;
    int row = c >> 3;
    int kc = (c & 7) ^ (row & 7);
    srcRel[t] = row * D + kc * 8;
  }

  float minS[16], maxD[16];
#pragma unroll
  for (int i = 0; i < 16; ++i) { minS[i] = 4.0f; maxD[i] = -4.0f; }
  int famR[16];
#pragma unroll
  for (int mi = 0; mi < 4; ++mi)
#pragma unroll
    for (int r = 0; r < 4; ++r)
      famR[mi * 4 + r] = fam[r0 + mi * 16 + q * 4 + r];

#pragma unroll 1
  for (int ci = 0; ci < CTG; ++ci) {
    const int c0 = (cg * CTG + ci) * 64;
    const unsigned short* Bsrc = Eh + (long)c0 * D;

    floatx4 acc[4][4];
#pragma unroll
    for (int mi = 0; mi < 4; ++mi)
#pragma unroll
      for (int nj = 0; nj < 4; ++nj) acc[mi][nj] = (floatx4)0.0f;

#pragma unroll
    for (int kb = 0; kb < D; kb += 64) {
      __syncthreads();   // 1-wave: WAR drain before overwriting Bs
#pragma unroll
      for (int t = 0; t < 8; ++t)
        ld_g2l16(Bsrc + kb + srcRel[t], &Bs[t * 512]);
      // A fragments direct from global (k-contiguous per lane)
      half8 a[2][4];
#pragma unroll
      for (int kh = 0; kh < 2; ++kh)
#pragma unroll
        for (int mi = 0; mi < 4; ++mi)
          a[kh][mi] = *(const half8*)
              &Eh[(long)(r0 + mi * 16 + m) * D + kb + kh * 32 + q * 8];
      __syncthreads();   // 1-wave: vmcnt drain -> Bs valid
#pragma unroll
      for (int kh = 0; kh < 2; ++kh) {
        half8 b[4];
#pragma unroll
        for (int nj = 0; nj < 4; ++nj) {
          int row = nj * 16 + m;
          b[nj] = *(const half8*)
              &Bs[row * 64 + (((kh * 4 + q) ^ (row & 7)) << 3)];
        }
#pragma unroll
        for (int mi = 0; mi < 4; ++mi)
#pragma unroll
          for (int nj = 0; nj < 4; ++nj)
            acc[mi][nj] = __builtin_amdgcn_mfma_f32_16x16x32_f16(
                a[kh][mi], b[nj], acc[mi][nj], 0, 0, 0);
      }
    }
    // fused epilogue for this 64x64 tile
    int famC[4];
#pragma unroll
    for (int nj = 0; nj < 4; ++nj) famC[nj] = fam[c0 + nj * 16 + m];
#pragma unroll
    for (int mi = 0; mi < 4; ++mi)
#pragma unroll
      for (int nj = 0; nj < 4; ++nj)
#pragma unroll
        for (int r = 0; r < 4; ++r) {
          float d = acc[mi][nj][r];          // C/D: col=l&15, row=q*4+r
          bool same = (famR[mi * 4 + r] == famC[nj]);
          minS[mi * 4 + r] = fminf(minS[mi * 4 + r], same ? d : 4.0f);
          maxD[mi * 4 + r] = fmaxf(maxD[mi * 4 + r], same ? -4.0f : d);
        }
  }
  // reduce across the 16 col lanes; write fp16-packed partials once
#pragma unroll
  for (int o = 1; o < 16; o <<= 1)
#pragma unroll
    for (int i = 0; i < 16; ++i) {
      minS[i] = fminf(minS[i], __shfl_xor(minS[i], o));
      maxD[i] = fmaxf(maxD[i], __shfl_xor(maxD[i], o));
    }
  if (m == 0) {
#pragma unroll
    for (int mi = 0; mi < 4; ++mi)
#pragma unroll
      for (int r = 0; r < 4; ++r) {
        int row = mi * 16 + q * 4 + r;
        unsigned lo = __builtin_bit_cast(unsigned short,
                                         (_Float16)minS[mi * 4 + r]);
        unsigned hi = __builtin_bit_cast(unsigned short,
                                         (_Float16)maxD[mi * 4 + r]);
        partMM[(long)cg * B + r0 + row] = lo | (hi << 16);
      }
  }
}

// K3: parallel per-row combine of ncg slices; block-reduce; atomicAdd
__global__ __launch_bounds__(128) void reduce_kernel(
    const unsigned* __restrict__ partMM, float* __restrict__ sumAcc,
    int* __restrict__ cntAcc, int B, int nsl) {
  int r = blockIdx.x * 128 + threadIdx.x;
  float mn = 4.0f, mx = -4.0f;
  for (int s = 0; s < nsl; ++s) {
    unsigned p = partMM[(long)s * B + r];
    mn = fminf(mn, (float)__builtin_bit_cast(_Float16,
                                             (unsigned short)(p & 0xFFFF)));
    mx = fmaxf(mx, (float)__builtin_bit_cast(_Float16,
                                             (unsigned short)(p >> 16)));
  }
  float loss = 0.0f;
  int c = 0;
  if (mn < 3.0f && mx > -3.0f) {   // has same && has diff
    loss = fmaxf(mx - mn + MARGIN, 0.0f);
    c = 1;
  }
#pragma unroll
  for (int o = 1; o < 64; o <<= 1) {
    loss += __shfl_xor(loss, o);
    c    += __shfl_xor(c, o);
  }
  __shared__ float ls[2];
  __shared__ int   cs[2];
  if ((threadIdx.x & 63) == 0) {
    ls[threadIdx.x >> 6] = loss;
    cs[threadIdx.x >> 6] = c;
  }
  __syncthreads();
  if (threadIdx.x == 0) {
    atomicAdd(sumAcc, ls[0] + ls[1]);
    atomicAdd(cntAcc, cs[0] + cs[1]);
  }
}

// K4: final divide
__global__ void final_kernel(const float* __restrict__ sumAcc,
                             const int* __restrict__ cntAcc,
                             float* __restrict__ out) {
  if (threadIdx.x == 0) {
    int c = cntAcc[0];
    out[0] = sumAcc[0] / (float)(c > 0 ? c : 1);
  }
}

extern "C" void kernel_launch(void* const* d_in, const int* in_sizes, int n_in,
                              void* d_out, int out_size, void* d_ws, size_t ws_size,
                              hipStream_t stream) {
  const float* E      = (const float*)d_in[0];
  const int*   labels = (const int*)d_in[1];
  float*       out    = (float*)d_out;
  const int B = in_sizes[1];   // 8192
  const int nsl = (B / 64) / CTG;   // 32 slices

  // ws: Eh[B*D] fp16 (4MB) | fam[B] | partMM[nsl*B] uint (1MB) | sum | cnt
  unsigned short* Eh = (unsigned short*)d_ws;
  int* fam           = (int*)(Eh + (size_t)B * D);
  unsigned* partMM   = (unsigned*)(fam + B);
  float* sumAcc      = (float*)(partMM + (size_t)nsl * B);
  int* cntAcc        = (int*)(sumAcc + 1);

  prep_kernel<<<dim3(B / 4), 256, 0, stream>>>(E, labels, Eh, fam,
                                               sumAcc, cntAcc, B);
  gram_kernel<<<dim3((B / 64) * nsl), 64, 0, stream>>>(Eh, fam, partMM, B);
  reduce_kernel<<<dim3(B / 128), 128, 0, stream>>>(partMM, sumAcc, cntAcc,
                                                   B, nsl);
  final_kernel<<<1, 64, 0, stream>>>(sumAcc, cntAcc, out);
}